// Round 5
// baseline (295.644 us; speedup 1.0000x reference)
//
#include <hip/hip_runtime.h>
#include <hip/hip_bf16.h>

// ---------------------------------------------------------------------------
// 2-layer GraphConv (DGL norm='both') + mean_nodes pool + linear classifier.
// N=80000, E=1.28M, D=H=64, C=5, G=512.
// R16: R15 falsified the spill theory (VGPR dropped to 56 with a 168 budget;
// compiler re-loads W from L1 per node) and the VALU theory (VALUBusy 35%,
// down from 42, dur flat). Profile = latency-bound serial chain per node:
// col-shfl -> random 16B gathers at L3/HBM latency (63MB HBM fetch: 10MB xs
// doesn't fit 4MB/XCD L2) -> 3-round butterfly -> GEMV -> 3-round scatter,
// ONE node in flight per wave. Fix: TWO nodes per wave, gathers issued
// back-to-back (2x memory-level parallelism), epilogue chains independent
// (shfl latencies overlap). Adjacent pairs keep bucket locality. Predicated
// dual-gather; rare deg>64 handled by the chunked loop as before.
// pA_scatter / p5_build / cls unchanged.
// ---------------------------------------------------------------------------

#define NBK 160            // max buckets: ceil(80000/512)=157 <= 160
#define HB  256            // edge-pass blocks in pA
#define CAP 9216           // per-bucket slot capacity (mean 8192, +11 sigma)

typedef __attribute__((ext_vector_type(8))) short bf16x8;
typedef __attribute__((ext_vector_type(4))) float f32x4;

__device__ __forceinline__ float bflo(unsigned u) { return __uint_as_float(u << 16); }
__device__ __forceinline__ float bfhi(unsigned u) { return __uint_as_float(u & 0xffff0000u); }
__device__ __forceinline__ float bf1(unsigned short u) { return __uint_as_float((unsigned)u << 16); }
__device__ __forceinline__ unsigned short f2bf(float f) {   // RNE
    unsigned u = __float_as_uint(f);
    return (unsigned short)((u + 0x7fff + ((u >> 16) & 1)) >> 16);
}

// --- pA: single-pass bucket scatter (blocks < HB) + graph bounds (rest) ----
__global__ __launch_bounds__(256) void pA_scatter(
    const int* __restrict__ src, const int* __restrict__ dst,
    int* __restrict__ curD, int* __restrict__ curS,       // NBK cursors each, pre-zeroed
    int* __restrict__ pack, unsigned short* __restrict__ sloc,
    const int* __restrict__ gids, int* __restrict__ goffs,
    int E, int NB, int N, int G)
{
    if (blockIdx.x >= HB) {                  // fused bounds_kernel
        int i = (blockIdx.x - HB) * 256 + threadIdx.x;
        if (i >= N) return;
        int b = gids[i];
        if (i == 0) {
            for (int g = 0; g <= b; g++) goffs[g] = 0;
        } else {
            int a = gids[i - 1];
            for (int g = a + 1; g <= b; g++) goffs[g] = i;
        }
        if (i == N - 1) {
            for (int g = b + 1; g <= G; g++) goffs[g] = N;
        }
        return;
    }
    __shared__ int hd[NBK], hs[NBK];
    int t = threadIdx.x;
    for (int i = t; i < NB; i += 256) { hd[i] = 0; hs[i] = 0; }
    __syncthreads();
    int chunk = (E + HB - 1) / HB;
    int s0 = blockIdx.x * chunk, s1 = min(E, s0 + chunk);
    // vectorized histogram pass
    int q0 = s0 >> 2, q1 = s1 >> 2;          // s0 is 4-aligned (chunk%4==0)
    const int4* s4 = (const int4*)src;
    const int4* d4 = (const int4*)dst;
    for (int q = q0 + t; q < q1; q += 256) {
        int4 d = d4[q];
        int4 s = s4[q];
        atomicAdd(&hd[d.x >> 9], 1); atomicAdd(&hd[d.y >> 9], 1);
        atomicAdd(&hd[d.z >> 9], 1); atomicAdd(&hd[d.w >> 9], 1);
        atomicAdd(&hs[s.x >> 9], 1); atomicAdd(&hs[s.y >> 9], 1);
        atomicAdd(&hs[s.z >> 9], 1); atomicAdd(&hs[s.w >> 9], 1);
    }
    for (int i = (q1 << 2) + t; i < s1; i += 256) {   // tail
        atomicAdd(&hd[dst[i] >> 9], 1);
        atomicAdd(&hs[src[i] >> 9], 1);
    }
    __syncthreads();
    for (int b = t; b < NB; b += 256) {      // reserve global slots
        int cd = hd[b], cs = hs[b];
        hd[b] = cd ? atomicAdd(&curD[b], cd) : 0;   // device atomic, 1/bucket
        hs[b] = cs ? atomicAdd(&curS[b], cs) : 0;
    }
    __syncthreads();
    // vectorized scatter pass (chunk re-read is L2-hot)
    for (int q = q0 + t; q < q1; q += 256) {
        int4 d = d4[q];
        int4 s = s4[q];
        #pragma unroll
        for (int j = 0; j < 4; j++) {
            int ss = j == 0 ? s.x : j == 1 ? s.y : j == 2 ? s.z : s.w;
            int dd = j == 0 ? d.x : j == 1 ? d.y : j == 2 ? d.z : d.w;
            int bd = dd >> 9, bs = ss >> 9;
            int pd = atomicAdd(&hd[bd], 1);  // LDS atomic
            int ps = atomicAdd(&hs[bs], 1);  // LDS atomic
            if (pd < CAP) pack[(size_t)bd * CAP + pd] = ((dd & 511) << 17) | ss;
            if (ps < CAP) sloc[(size_t)bs * CAP + ps] = (unsigned short)(ss & 511);
        }
    }
    for (int i = (q1 << 2) + t; i < s1; i += 256) {   // tail
        int s = src[i], d = dst[i];
        int bd = d >> 9, bs = s >> 9;
        int pd = atomicAdd(&hd[bd], 1);
        int ps = atomicAdd(&hs[bs], 1);
        if (pd < CAP) pack[(size_t)bd * CAP + pd] = ((d & 511) << 17) | s;
        if (ps < CAP) sloc[(size_t)bs * CAP + ps] = (unsigned short)(s & 511);
    }
}

// --- p5: dst mode -> CSR (row_offs,deg,col,ndst); src mode -> nsrc+prescale -
__global__ __launch_bounds__(256) void p5_build(
    const int* __restrict__ pack, const unsigned short* __restrict__ sloc,
    const int* __restrict__ curD, const int* __restrict__ curS,
    int* __restrict__ col, int* __restrict__ row_offs, int* __restrict__ deg,
    float* __restrict__ nsrc, float* __restrict__ ndst,
    const float* __restrict__ h, unsigned short* __restrict__ xs,
    int N, int NB)
{
    __shared__ int hist[512];
    __shared__ float nsl[512];
    __shared__ int wt[4];
    int t = threadIdx.x;
    bool dmode = blockIdx.x < NB;
    int b = dmode ? blockIdx.x : blockIdx.x - NB;
    int n0 = b << 9, n1 = min(N, n0 + 512);
    hist[t] = 0; hist[t + 256] = 0;
    __syncthreads();
    int e0 = b * CAP;
    int tot = min(dmode ? curD[b] : curS[b], CAP);
    int e1 = e0 + tot;
    if (!dmode) {
        for (int i = e0 + t; i < e1; i += 256)
            atomicAdd(&hist[sloc[i]], 1);            // LDS atomic
        __syncthreads();
        for (int n = n0 + t; n < n1; n += 256) {
            float s = rsqrtf((float)max(hist[n - n0], 1));
            nsrc[n] = s;
            nsl[n - n0] = s;
        }
        __syncthreads();
        int cnt = n1 - n0;
        const float2* h2p = (const float2*)h;
        ushort2* xp = (ushort2*)xs;
        for (int i = t; i < cnt * 32; i += 256) {
            int node = i >> 5;
            float s = nsl[node];
            float2 v = h2p[(size_t)(n0 + node) * 32 + (i & 31)];
            ushort2 o;
            o.x = f2bf(v.x * s);
            o.y = f2bf(v.y * s);
            xp[(size_t)(n0 + node) * 32 + (i & 31)] = o;
        }
        return;
    }
    for (int i = e0 + t; i < e1; i += 256)
        atomicAdd(&hist[pack[i] >> 17], 1);          // LDS atomic
    __syncthreads();
    int c0 = hist[2 * t], c1 = hist[2 * t + 1];
    int v = c0 + c1;
    int lane = t & 63, w = t >> 6;
    int x = v;
    #pragma unroll
    for (int off = 1; off < 64; off <<= 1) {
        int y = __shfl_up(x, off);
        if (lane >= off) x += y;
    }
    if (lane == 63) wt[w] = x;
    __syncthreads();
    int bw = 0;
    for (int i = 0; i < w; i++) bw += wt[i];
    int excl = x - v + bw;
    int n = n0 + 2 * t;
    if (n < n1) {
        row_offs[n] = e0 + excl;
        deg[n] = c0;
        ndst[n] = rsqrtf((float)max(c0, 1));
    }
    if (n + 1 < n1) {
        row_offs[n + 1] = e0 + excl + c0;
        deg[n + 1] = c1;
        ndst[n + 1] = rsqrtf((float)max(c1, 1));
    }
    hist[2 * t] = excl;
    hist[2 * t + 1] = excl + c0;
    __syncthreads();
    for (int i = e0 + t; i < e1; i += 256) {
        int wd = pack[i];
        int pos = atomicAdd(&hist[wd >> 17], 1);     // LDS atomic
        col[e0 + pos] = wd & 0x1FFFF;
    }
}

// 3-step reduce-scatter over li bits: returns z[lane] from pz[8] partials
__device__ __forceinline__ float rscatter(const float pz[8], int lane)
{
    float q4[4];
    {
        int bit = lane & 1;
        #pragma unroll
        for (int p = 0; p < 4; p++) {
            float mine  = bit ? pz[2 * p + 1] : pz[2 * p];
            float yours = bit ? pz[2 * p]     : pz[2 * p + 1];
            q4[p] = mine + __shfl_xor(yours, 1);
        }
    }
    float q2[2];
    {
        int bit = (lane >> 1) & 1;
        #pragma unroll
        for (int p = 0; p < 2; p++) {
            float mine  = bit ? q4[2 * p + 1] : q4[2 * p];
            float yours = bit ? q4[2 * p]     : q4[2 * p + 1];
            q2[p] = mine + __shfl_xor(yours, 2);
        }
    }
    int bit = (lane >> 2) & 1;
    float mine  = bit ? q2[1] : q2[0];
    float yours = bit ? q2[0] : q2[1];
    return mine + __shfl_xor(yours, 4);
}

#define UNPACK8(av, v)                                    \
    av[0] += bflo(v.x); av[1] += bfhi(v.x);               \
    av[2] += bflo(v.y); av[3] += bfhi(v.y);               \
    av[4] += bflo(v.z); av[5] += bfhi(v.z);               \
    av[6] += bflo(v.w); av[7] += bfhi(v.w);

// --- fused gather-sum + row-local 64x64 GEMV, TWO nodes per wave -----------
// MODE 0: yout[node] = bf16(relu(nd*(s@W)+b) * ns)       (layer 1)
// MODE 1: atomicAdd(gacc[gids[node]], relu(nd*(s@W)+b))  (layer 2 + pool)
template<int MODE>
__global__ __launch_bounds__(256, 3) void agg_gemv(
    const unsigned short* __restrict__ zin, unsigned short* __restrict__ yout,
    const int* __restrict__ cols, const int* __restrict__ row_offs,
    const int* __restrict__ deg, const float* __restrict__ W,
    const float* __restrict__ bias, const float* __restrict__ ndst,
    const float* __restrict__ nsrc, const int* __restrict__ gids,
    float* __restrict__ gacc, int N)
{
    int lane = threadIdx.x & 63;
    int sub  = lane >> 3;
    int li   = lane & 7;
    float bv = bias[lane];

    // per-lane W fragment: wreg[r][j] = W[8*li+r][8*sub+j]
    float wreg[8][8];
    {
        const float4* w4 = (const float4*)W;
        #pragma unroll
        for (int r = 0; r < 8; r++) {
            float4 lo = w4[(8 * li + r) * 16 + 2 * sub];
            float4 hi = w4[(8 * li + r) * 16 + 2 * sub + 1];
            wreg[r][0] = lo.x; wreg[r][1] = lo.y; wreg[r][2] = lo.z; wreg[r][3] = lo.w;
            wreg[r][4] = hi.x; wreg[r][5] = hi.y; wreg[r][6] = hi.z; wreg[r][7] = hi.w;
        }
    }

    const uint4* x4 = (const uint4*)zin;

    int wv  = (blockIdx.x * 256 + threadIdx.x) >> 6;
    int nwv = (gridDim.x * 256) >> 6;
    int step = 2 * nwv;

    int base = 2 * wv;
    int roA = 0, cntA = 0, idxA = 0, roB = 0, cntB = 0, idxB = 0;
    if (base < N) {
        roA = row_offs[base]; cntA = deg[base];
        if (lane < min(cntA, 64)) idxA = cols[roA + lane];
    }
    if (base + 1 < N) {
        roB = row_offs[base + 1]; cntB = deg[base + 1];
        if (lane < min(cntB, 64)) idxB = cols[roB + lane];
    }

    for (; base < N; base += step) {
        int nA = base, nB = base + 1;
        bool vB = nB < N;
        int nbase = base + step;
        int nroA = 0, ncntA = 0, nroB = 0, ncntB = 0;
        if (nbase < N)     { nroA = row_offs[nbase];     ncntA = deg[nbase]; }
        if (nbase + 1 < N) { nroB = row_offs[nbase + 1]; ncntB = deg[nbase + 1]; }

        float avA[8] = {0.f,0.f,0.f,0.f,0.f,0.f,0.f,0.f};
        float avB[8] = {0.f,0.f,0.f,0.f,0.f,0.f,0.f,0.f};
        int ccA = 0, ccB = 0;
        int cidxA = idxA, cidxB = idxB;
        while (ccA < cntA || ccB < cntB) {
            int mA = min(cntA - ccA, 64);       // may be <= 0 (exhausted)
            int mB = min(cntB - ccB, 64);
            int mm = max(mA, mB);
            for (int i = 0; i < mm; i += 16) {
                int e1 = i + sub, e2 = i + 8 + sub;
                // &63 makes the shfl index safe when m-1 == -1 (unused result)
                int sA1 = __shfl(cidxA, min(e1, mA - 1) & 63);
                int sA2 = __shfl(cidxA, min(e2, mA - 1) & 63);
                int sB1 = __shfl(cidxB, min(e1, mB - 1) & 63);
                int sB2 = __shfl(cidxB, min(e2, mB - 1) & 63);
                uint4 vA1 = make_uint4(0u,0u,0u,0u), vA2 = vA1;
                uint4 vB1 = vA1, vB2 = vA1;
                // all four loads issue before any unpack needs them (2x MLP)
                if (e1 < mA) vA1 = x4[(size_t)sA1 * 8 + li];
                if (e2 < mA) vA2 = x4[(size_t)sA2 * 8 + li];
                if (e1 < mB) vB1 = x4[(size_t)sB1 * 8 + li];
                if (e2 < mB) vB2 = x4[(size_t)sB2 * 8 + li];
                UNPACK8(avA, vA1); UNPACK8(avA, vA2);
                UNPACK8(avB, vB1); UNPACK8(avB, vB2);
            }
            ccA += 64; ccB += 64;
            if (ccA < cntA) cidxA = (lane < min(cntA - ccA, 64)) ? cols[roA + ccA + lane] : 0;
            if (ccB < cntB) cidxB = (lane < min(cntB - ccB, 64)) ? cols[roB + ccB + lane] : 0;
        }

        // prefetch next pair's cols during the epilogue
        idxA = 0; idxB = 0;
        if (nbase < N && lane < min(ncntA, 64))     idxA = cols[nroA + lane];
        if (nbase + 1 < N && lane < min(ncntB, 64)) idxB = cols[nroB + lane];

        // butterflies (independent chains -> latencies overlap)
        #pragma unroll
        for (int off = 8; off <= 32; off <<= 1) {
            #pragma unroll
            for (int r = 0; r < 8; r++) avA[r] += __shfl_xor(avA[r], off);
            #pragma unroll
            for (int r = 0; r < 8; r++) avB[r] += __shfl_xor(avB[r], off);
        }

        // GEMVs (lane-local)
        float pzA[8], pzB[8];
        #pragma unroll
        for (int j = 0; j < 8; j++) {
            float a = 0.f, b = 0.f;
            #pragma unroll
            for (int r = 0; r < 8; r++) {
                a = fmaf(avA[r], wreg[r][j], a);
                b = fmaf(avB[r], wreg[r][j], b);
            }
            pzA[j] = a; pzB[j] = b;
        }
        float zA = rscatter(pzA, lane);
        float zB = rscatter(pzB, lane);

        zA = fmaxf(ndst[nA] * zA + bv, 0.f);
        if (MODE == 0) {
            zA *= nsrc[nA];
            int u = (int)f2bf(zA);
            int o = u | (__shfl_down(u, 1) << 16);
            if (!(lane & 1))
                ((unsigned*)yout)[(size_t)nA * 32 + (lane >> 1)] = (unsigned)o;
        } else {
            atomicAdd(&gacc[(size_t)gids[nA] * 64 + lane], zA);
        }
        if (vB) {
            zB = fmaxf(ndst[nB] * zB + bv, 0.f);
            if (MODE == 0) {
                zB *= nsrc[nB];
                int u = (int)f2bf(zB);
                int o = u | (__shfl_down(u, 1) << 16);
                if (!(lane & 1))
                    ((unsigned*)yout)[(size_t)nB * 32 + (lane >> 1)] = (unsigned)o;
            } else {
                atomicAdd(&gacc[(size_t)gids[nB] * 64 + lane], zB);
            }
        }
        roA = nroA; cntA = ncntA; roB = nroB; cntB = ncntB;
    }
}

// --- per-graph mean + 64x5 classifier (1 wave per graph) -------------------
__global__ __launch_bounds__(64) void cls_kernel(
    const float* __restrict__ gacc, const int* __restrict__ goffs,
    const float* __restrict__ Wc, const float* __restrict__ bc,
    float* __restrict__ out, int G)
{
    int g = blockIdx.x;
    int lane = threadIdx.x;
    float cnt = (float)max(goffs[g + 1] - goffs[g], 1);
    float mean = gacc[(size_t)g * 64 + lane] / cnt;
    #pragma unroll
    for (int c = 0; c < 5; c++) {
        float p = mean * Wc[lane * 5 + c];
        #pragma unroll
        for (int off = 32; off; off >>= 1) p += __shfl_down(p, off);
        if (lane == 0) out[g * 5 + c] = p + bc[c];
    }
}

extern "C" void kernel_launch(void* const* d_in, const int* in_sizes, int n_in,
                              void* d_out, int out_size, void* d_ws, size_t ws_size,
                              hipStream_t stream)
{
    const float* h    = (const float*)d_in[0];
    const int*   src  = (const int*)d_in[1];
    const int*   dst  = (const int*)d_in[2];
    const int*   gids = (const int*)d_in[3];
    const float* W1   = (const float*)d_in[4];
    const float* b1   = (const float*)d_in[5];
    const float* W2   = (const float*)d_in[6];
    const float* b2   = (const float*)d_in[7];
    const float* Wc   = (const float*)d_in[8];
    const float* bc   = (const float*)d_in[9];
    float* out = (float*)d_out;

    const int N = in_sizes[0] / 64;
    const int E = in_sizes[1];
    const int G = out_size / 5;
    const int NB = (N + 511) >> 9;
    const int NBB = (N + 255) / 256;        // bounds blocks

    auto align = [](size_t x) { return (x + 255) & ~(size_t)255; };
    char* p = (char*)d_ws;
    // curD | curS | gacc contiguous -> single memset clears all three
    int* curD    = (int*)p;
    int* curS    = curD + NBK;
    float* gacc  = (float*)(p + (size_t)2 * NBK * 4);   // G*64 floats
    size_t zbytes = (size_t)2 * NBK * 4 + (size_t)G * 64 * 4;
    p += align(zbytes);
    int* row_offs= (int*)p;            p += align((size_t)N * 4);
    int* deg     = (int*)p;            p += align((size_t)N * 4);
    float* nsrc  = (float*)p;          p += align((size_t)N * 4);
    float* ndst  = (float*)p;          p += align((size_t)N * 4);
    int* goffs   = (int*)p;            p += align((size_t)(G + 1) * 4);
    int* pack    = (int*)p;            p += align((size_t)NBK * CAP * 4);
    unsigned short* sloc = (unsigned short*)p; p += align((size_t)NBK * CAP * 2);
    int* cols    = (int*)p;            p += align((size_t)NBK * CAP * 4);
    unsigned short* xs  = (unsigned short*)p; p += align((size_t)N * 64 * 2);
    unsigned short* h1s = (unsigned short*)p; p += align((size_t)N * 64 * 2);

    hipMemsetAsync(curD, 0, zbytes, stream);

    pA_scatter<<<HB + NBB, 256, 0, stream>>>(src, dst, curD, curS, pack, sloc,
                                             gids, goffs, E, NB, N, G);
    p5_build<<<2 * NB, 256, 0, stream>>>(pack, sloc, curD, curS, cols,
                                         row_offs, deg, nsrc, ndst, h, xs, N, NB);

    agg_gemv<0><<<4096, 256, 0, stream>>>(xs, h1s, cols, row_offs, deg,
                                          W1, b1, ndst, nsrc, nullptr, nullptr, N);
    agg_gemv<1><<<4096, 256, 0, stream>>>(h1s, nullptr, cols, row_offs, deg,
                                          W2, b2, ndst, nullptr, gids, gacc, N);
    cls_kernel<<<G, 64, 0, stream>>>(gacc, goffs, Wc, bc, out, G);
}

// Round 6
// 290.798 us; speedup vs baseline: 1.0167x; 1.0167x over previous
//
#include <hip/hip_runtime.h>
#include <hip/hip_bf16.h>

// ---------------------------------------------------------------------------
// 2-layer GraphConv (DGL norm='both') + mean_nodes pool + linear classifier.
// N=80000, E=1.28M, D=H=64, C=5, G=512.
// R17: cross-round arithmetic shows the R13-16 fused agg+GEMV was a NET LOSS:
// R11 (separate agg + MFMA gemm + extra pool kernel + h2 round-trip) = 224us
// vs best fused pipeline 274us, same pA/p5. The in-wave GEMV epilogue
// (24-shfl butterfly + 64 FMA + 7-shfl scatter, serialized per node) costs
// ~+20us/layer; the standalone MFMA gemm pass costs ~8us. REVERT to R11's
// agg_kernel + gemm_kernel, keeping only the validated post-R11 wins:
//  (a) gemm2 epilogue atomicAdd's relu output into gacc[graph][64] (5.1M f32
//      atomics over 32K addrs -- proven fine in R13-16 MODE1) => kills the
//      10MB h2 write, 10MB pool read, and the pool kernel;
//  (b) tiny cls_kernel; single contiguous memset (cursors + gacc).
// pA_scatter / p5_build / agg_kernel are R11-verbatim.
// ---------------------------------------------------------------------------

#define NBK 160            // max buckets: ceil(80000/512)=157 <= 160
#define HB  256            // edge-pass blocks in pA
#define CAP 9216           // per-bucket slot capacity (mean 8192, +11 sigma)

typedef __attribute__((ext_vector_type(8))) short bf16x8;
typedef __attribute__((ext_vector_type(4))) float f32x4;

__device__ __forceinline__ float bflo(unsigned u) { return __uint_as_float(u << 16); }
__device__ __forceinline__ float bfhi(unsigned u) { return __uint_as_float(u & 0xffff0000u); }
__device__ __forceinline__ float bf1(unsigned short u) { return __uint_as_float((unsigned)u << 16); }
__device__ __forceinline__ unsigned short f2bf(float f) {   // RNE
    unsigned u = __float_as_uint(f);
    return (unsigned short)((u + 0x7fff + ((u >> 16) & 1)) >> 16);
}
__device__ __forceinline__ unsigned packbf(float lo, float hi) {
    return (unsigned)f2bf(lo) | ((unsigned)f2bf(hi) << 16);
}

// --- pA: single-pass bucket scatter (blocks < HB) + graph bounds (rest) ----
__global__ __launch_bounds__(256) void pA_scatter(
    const int* __restrict__ src, const int* __restrict__ dst,
    int* __restrict__ curD, int* __restrict__ curS,       // NBK cursors each, pre-zeroed
    int* __restrict__ pack, unsigned short* __restrict__ sloc,
    const int* __restrict__ gids, int* __restrict__ goffs,
    int E, int NB, int N, int G)
{
    if (blockIdx.x >= HB) {                  // fused bounds_kernel
        int i = (blockIdx.x - HB) * 256 + threadIdx.x;
        if (i >= N) return;
        int b = gids[i];
        if (i == 0) {
            for (int g = 0; g <= b; g++) goffs[g] = 0;
        } else {
            int a = gids[i - 1];
            for (int g = a + 1; g <= b; g++) goffs[g] = i;
        }
        if (i == N - 1) {
            for (int g = b + 1; g <= G; g++) goffs[g] = N;
        }
        return;
    }
    __shared__ int hd[NBK], hs[NBK];
    int t = threadIdx.x;
    for (int i = t; i < NB; i += 256) { hd[i] = 0; hs[i] = 0; }
    __syncthreads();
    int chunk = (E + HB - 1) / HB;
    int s0 = blockIdx.x * chunk, s1 = min(E, s0 + chunk);
    // vectorized histogram pass
    int q0 = s0 >> 2, q1 = s1 >> 2;          // s0 is 4-aligned (chunk%4==0)
    const int4* s4 = (const int4*)src;
    const int4* d4 = (const int4*)dst;
    for (int q = q0 + t; q < q1; q += 256) {
        int4 d = d4[q];
        int4 s = s4[q];
        atomicAdd(&hd[d.x >> 9], 1); atomicAdd(&hd[d.y >> 9], 1);
        atomicAdd(&hd[d.z >> 9], 1); atomicAdd(&hd[d.w >> 9], 1);
        atomicAdd(&hs[s.x >> 9], 1); atomicAdd(&hs[s.y >> 9], 1);
        atomicAdd(&hs[s.z >> 9], 1); atomicAdd(&hs[s.w >> 9], 1);
    }
    for (int i = (q1 << 2) + t; i < s1; i += 256) {   // tail
        atomicAdd(&hd[dst[i] >> 9], 1);
        atomicAdd(&hs[src[i] >> 9], 1);
    }
    __syncthreads();
    for (int b = t; b < NB; b += 256) {      // reserve global slots
        int cd = hd[b], cs = hs[b];
        hd[b] = cd ? atomicAdd(&curD[b], cd) : 0;   // device atomic, 1/bucket
        hs[b] = cs ? atomicAdd(&curS[b], cs) : 0;
    }
    __syncthreads();
    // vectorized scatter pass (chunk re-read is L2-hot)
    for (int q = q0 + t; q < q1; q += 256) {
        int4 d = d4[q];
        int4 s = s4[q];
        #pragma unroll
        for (int j = 0; j < 4; j++) {
            int ss = j == 0 ? s.x : j == 1 ? s.y : j == 2 ? s.z : s.w;
            int dd = j == 0 ? d.x : j == 1 ? d.y : j == 2 ? d.z : d.w;
            int bd = dd >> 9, bs = ss >> 9;
            int pd = atomicAdd(&hd[bd], 1);  // LDS atomic
            int ps = atomicAdd(&hs[bs], 1);  // LDS atomic
            if (pd < CAP) pack[(size_t)bd * CAP + pd] = ((dd & 511) << 17) | ss;
            if (ps < CAP) sloc[(size_t)bs * CAP + ps] = (unsigned short)(ss & 511);
        }
    }
    for (int i = (q1 << 2) + t; i < s1; i += 256) {   // tail
        int s = src[i], d = dst[i];
        int bd = d >> 9, bs = s >> 9;
        int pd = atomicAdd(&hd[bd], 1);
        int ps = atomicAdd(&hs[bs], 1);
        if (pd < CAP) pack[(size_t)bd * CAP + pd] = ((d & 511) << 17) | s;
        if (ps < CAP) sloc[(size_t)bs * CAP + ps] = (unsigned short)(s & 511);
    }
}

// --- p5: dst mode -> CSR (row_offs,deg,col,ndst); src mode -> nsrc+prescale -
__global__ __launch_bounds__(256) void p5_build(
    const int* __restrict__ pack, const unsigned short* __restrict__ sloc,
    const int* __restrict__ curD, const int* __restrict__ curS,
    int* __restrict__ col, int* __restrict__ row_offs, int* __restrict__ deg,
    float* __restrict__ nsrc, float* __restrict__ ndst,
    const float* __restrict__ h, unsigned short* __restrict__ xs,
    int N, int NB)
{
    __shared__ int hist[512];
    __shared__ float nsl[512];
    __shared__ int wt[4];
    int t = threadIdx.x;
    bool dmode = blockIdx.x < NB;
    int b = dmode ? blockIdx.x : blockIdx.x - NB;
    int n0 = b << 9, n1 = min(N, n0 + 512);
    hist[t] = 0; hist[t + 256] = 0;
    __syncthreads();
    int e0 = b * CAP;
    int tot = min(dmode ? curD[b] : curS[b], CAP);
    int e1 = e0 + tot;
    if (!dmode) {
        for (int i = e0 + t; i < e1; i += 256)
            atomicAdd(&hist[sloc[i]], 1);            // LDS atomic
        __syncthreads();
        for (int n = n0 + t; n < n1; n += 256) {
            float s = rsqrtf((float)max(hist[n - n0], 1));
            nsrc[n] = s;
            nsl[n - n0] = s;
        }
        __syncthreads();
        int cnt = n1 - n0;
        const float2* h2p = (const float2*)h;
        ushort2* xp = (ushort2*)xs;
        for (int i = t; i < cnt * 32; i += 256) {
            int node = i >> 5;
            float s = nsl[node];
            float2 v = h2p[(size_t)(n0 + node) * 32 + (i & 31)];
            ushort2 o;
            o.x = f2bf(v.x * s);
            o.y = f2bf(v.y * s);
            xp[(size_t)(n0 + node) * 32 + (i & 31)] = o;
        }
        return;
    }
    for (int i = e0 + t; i < e1; i += 256)
        atomicAdd(&hist[pack[i] >> 17], 1);          // LDS atomic
    __syncthreads();
    int c0 = hist[2 * t], c1 = hist[2 * t + 1];
    int v = c0 + c1;
    int lane = t & 63, w = t >> 6;
    int x = v;
    #pragma unroll
    for (int off = 1; off < 64; off <<= 1) {
        int y = __shfl_up(x, off);
        if (lane >= off) x += y;
    }
    if (lane == 63) wt[w] = x;
    __syncthreads();
    int bw = 0;
    for (int i = 0; i < w; i++) bw += wt[i];
    int excl = x - v + bw;
    int n = n0 + 2 * t;
    if (n < n1) {
        row_offs[n] = e0 + excl;
        deg[n] = c0;
        ndst[n] = rsqrtf((float)max(c0, 1));
    }
    if (n + 1 < n1) {
        row_offs[n + 1] = e0 + excl + c0;
        deg[n + 1] = c1;
        ndst[n + 1] = rsqrtf((float)max(c1, 1));
    }
    hist[2 * t] = excl;
    hist[2 * t + 1] = excl + c0;
    __syncthreads();
    for (int i = e0 + t; i < e1; i += 256) {
        int wd = pack[i];
        int pos = atomicAdd(&hist[wd >> 17], 1);     // LDS atomic
        col[e0 + pos] = wd & 0x1FFFF;
    }
}

// --- pure gather-sum with next-node prefetch (R11-verbatim) ----------------
__global__ __launch_bounds__(256) void agg_kernel(
    const unsigned short* __restrict__ z, unsigned short* __restrict__ y,
    const int* __restrict__ col, const int* __restrict__ row_offs,
    const int* __restrict__ deg, int N)
{
    int lane = threadIdx.x & 63;
    int sub  = lane >> 3;
    int li   = lane & 7;
    const uint4* x4 = (const uint4*)z;

    int wid = (blockIdx.x * 256 + threadIdx.x) >> 6;
    int nw  = (gridDim.x * 256) >> 6;

    int ro = 0, cnt = 0, idx = 0;
    if (wid < N) {
        ro = row_offs[wid];
        cnt = deg[wid];
        if (lane < min(cnt, 64)) idx = col[ro + lane];
    }
    for (int node = wid; node < N; node += nw) {
        int nnode = node + nw;
        int nro = 0, ncnt = 0;
        if (nnode < N) { nro = row_offs[nnode]; ncnt = deg[nnode]; }  // prefetch

        float a0=0.f,a1=0.f,a2=0.f,a3=0.f,a4=0.f,a5=0.f,a6=0.f,a7=0.f;
        int cc = 0;
        int cidx = idx;
        while (cc < cnt) {
            int m = min(cnt - cc, 64);
            for (int i = 0; i < m; i += 32) {
                int e1 = i + sub, e2 = i + 8 + sub, e3 = i + 16 + sub, e4 = i + 24 + sub;
                int s1 = __shfl(cidx, min(e1, m - 1));
                int s2 = __shfl(cidx, min(e2, m - 1));
                int s3 = __shfl(cidx, min(e3, m - 1));
                int s4 = __shfl(cidx, min(e4, m - 1));
                uint4 v1 = make_uint4(0u,0u,0u,0u), v2 = v1, v3 = v1, v4 = v1;
                if (e1 < m) v1 = x4[(size_t)s1 * 8 + li];
                if (e2 < m) v2 = x4[(size_t)s2 * 8 + li];
                if (e3 < m) v3 = x4[(size_t)s3 * 8 + li];
                if (e4 < m) v4 = x4[(size_t)s4 * 8 + li];
                a0 += bflo(v1.x); a1 += bfhi(v1.x);
                a2 += bflo(v1.y); a3 += bfhi(v1.y);
                a4 += bflo(v1.z); a5 += bfhi(v1.z);
                a6 += bflo(v1.w); a7 += bfhi(v1.w);
                a0 += bflo(v2.x); a1 += bfhi(v2.x);
                a2 += bflo(v2.y); a3 += bfhi(v2.y);
                a4 += bflo(v2.z); a5 += bfhi(v2.z);
                a6 += bflo(v2.w); a7 += bfhi(v2.w);
                a0 += bflo(v3.x); a1 += bfhi(v3.x);
                a2 += bflo(v3.y); a3 += bfhi(v3.y);
                a4 += bflo(v3.z); a5 += bfhi(v3.z);
                a6 += bflo(v3.w); a7 += bfhi(v3.w);
                a0 += bflo(v4.x); a1 += bfhi(v4.x);
                a2 += bflo(v4.y); a3 += bfhi(v4.y);
                a4 += bflo(v4.z); a5 += bfhi(v4.z);
                a6 += bflo(v4.w); a7 += bfhi(v4.w);
            }
            cc += 64;
            if (cc < cnt) cidx = (lane < min(cnt - cc, 64)) ? col[ro + cc + lane] : 0;
        }
        // prefetch next node's col during the reduce
        idx = 0;
        if (nnode < N && lane < min(ncnt, 64)) idx = col[nro + lane];

        #pragma unroll
        for (int off = 8; off <= 32; off <<= 1) {
            a0 += __shfl_xor(a0, off); a1 += __shfl_xor(a1, off);
            a2 += __shfl_xor(a2, off); a3 += __shfl_xor(a3, off);
            a4 += __shfl_xor(a4, off); a5 += __shfl_xor(a5, off);
            a6 += __shfl_xor(a6, off); a7 += __shfl_xor(a7, off);
        }
        if (sub == 0) {                       // 8 lanes store the 128B row
            uint4 o;
            o.x = packbf(a0, a1);
            o.y = packbf(a2, a3);
            o.z = packbf(a4, a5);
            o.w = packbf(a6, a7);
            ((uint4*)y)[(size_t)node * 8 + li] = o;
        }
        ro = nro; cnt = ncnt;
    }
}

// --- GEMM + epilogue -------------------------------------------------------
// POOL=0: Z[m] = bf16(relu(ndst[m]*(S[m]@W) + b) * nsrc[m])   (layer 1)
// POOL=1: atomicAdd(gacc[gids[m]*64 + c], relu(ndst[m]*(S[m]@W) + b))
template<int POOL>
__global__ __launch_bounds__(256) void gemm_kernel(
    const unsigned short* __restrict__ A, const float* __restrict__ W,
    const float* __restrict__ b, const float* __restrict__ ndst,
    const float* __restrict__ nsrc, unsigned short* __restrict__ Z,
    const int* __restrict__ gids, float* __restrict__ gacc, int M)
{
    int t = threadIdx.x, lane = t & 63, w = t >> 6;
    int col = lane & 15, quad = lane >> 4;
    bf16x8 bfrag[4][2];
    #pragma unroll
    for (int nt = 0; nt < 4; nt++)
        #pragma unroll
        for (int ks = 0; ks < 2; ks++)
            #pragma unroll
            for (int j = 0; j < 8; j++)
                bfrag[nt][ks][j] =
                    (short)f2bf(W[(ks * 32 + quad * 8 + j) * 64 + nt * 16 + col]);
    float bias[4];
    #pragma unroll
    for (int nt = 0; nt < 4; nt++) bias[nt] = b[nt * 16 + col];

    int mbase = blockIdx.x * 64 + w * 16;
    if (mbase >= M) return;
    int row = min(mbase + col, M - 1);
    const uint4* a4 = (const uint4*)A;
    union { uint4 u; bf16x8 v; } a0, a1;
    a0.u = a4[(size_t)row * 8 + quad];
    a1.u = a4[(size_t)row * 8 + 4 + quad];

    float nd[4], ns[4];
    int gg[4];
    #pragma unroll
    for (int r = 0; r < 4; r++) {
        int m = min(mbase + quad * 4 + r, M - 1);
        nd[r] = ndst[m];
        ns[r] = POOL ? 1.f : nsrc[m];
        gg[r] = POOL ? gids[m] : 0;
    }

    #pragma unroll
    for (int nt = 0; nt < 4; nt++) {
        f32x4 acc = {0.f, 0.f, 0.f, 0.f};
        acc = __builtin_amdgcn_mfma_f32_16x16x32_bf16(a0.v, bfrag[nt][0], acc, 0, 0, 0);
        acc = __builtin_amdgcn_mfma_f32_16x16x32_bf16(a1.v, bfrag[nt][1], acc, 0, 0, 0);
        #pragma unroll
        for (int r = 0; r < 4; r++) {
            int m = mbase + quad * 4 + r;
            if (m < M) {
                float v = fmaxf(nd[r] * acc[r] + bias[nt], 0.f);
                if (POOL)
                    atomicAdd(&gacc[(size_t)gg[r] * 64 + nt * 16 + col], v);
                else
                    Z[(size_t)m * 64 + nt * 16 + col] = f2bf(v * ns[r]);
            }
        }
    }
}

// --- per-graph mean + 64x5 classifier (1 wave per graph) -------------------
__global__ __launch_bounds__(64) void cls_kernel(
    const float* __restrict__ gacc, const int* __restrict__ goffs,
    const float* __restrict__ Wc, const float* __restrict__ bc,
    float* __restrict__ out, int G)
{
    int g = blockIdx.x;
    int lane = threadIdx.x;
    float cnt = (float)max(goffs[g + 1] - goffs[g], 1);
    float mean = gacc[(size_t)g * 64 + lane] / cnt;
    #pragma unroll
    for (int c = 0; c < 5; c++) {
        float p = mean * Wc[lane * 5 + c];
        #pragma unroll
        for (int off = 32; off; off >>= 1) p += __shfl_down(p, off);
        if (lane == 0) out[g * 5 + c] = p + bc[c];
    }
}

extern "C" void kernel_launch(void* const* d_in, const int* in_sizes, int n_in,
                              void* d_out, int out_size, void* d_ws, size_t ws_size,
                              hipStream_t stream)
{
    const float* h    = (const float*)d_in[0];
    const int*   src  = (const int*)d_in[1];
    const int*   dst  = (const int*)d_in[2];
    const int*   gids = (const int*)d_in[3];
    const float* W1   = (const float*)d_in[4];
    const float* b1   = (const float*)d_in[5];
    const float* W2   = (const float*)d_in[6];
    const float* b2   = (const float*)d_in[7];
    const float* Wc   = (const float*)d_in[8];
    const float* bc   = (const float*)d_in[9];
    float* out = (float*)d_out;

    const int N = in_sizes[0] / 64;
    const int E = in_sizes[1];
    const int G = out_size / 5;
    const int NB = (N + 511) >> 9;
    const int NBB = (N + 255) / 256;        // bounds blocks

    auto align = [](size_t x) { return (x + 255) & ~(size_t)255; };
    char* p = (char*)d_ws;
    // curD | curS | gacc contiguous -> single memset clears all three
    int* curD    = (int*)p;
    int* curS    = curD + NBK;
    float* gacc  = (float*)(p + (size_t)2 * NBK * 4);   // G*64 floats
    size_t zbytes = (size_t)2 * NBK * 4 + (size_t)G * 64 * 4;
    p += align(zbytes);
    int* row_offs= (int*)p;            p += align((size_t)N * 4);
    int* deg     = (int*)p;            p += align((size_t)N * 4);
    float* nsrc  = (float*)p;          p += align((size_t)N * 4);
    float* ndst  = (float*)p;          p += align((size_t)N * 4);
    int* goffs   = (int*)p;            p += align((size_t)(G + 1) * 4);
    int* pack    = (int*)p;            p += align((size_t)NBK * CAP * 4);
    unsigned short* sloc = (unsigned short*)p; p += align((size_t)NBK * CAP * 2);
    int* cols    = (int*)p;            p += align((size_t)NBK * CAP * 4);
    unsigned short* xs  = (unsigned short*)p; p += align((size_t)N * 64 * 2);
    unsigned short* s1  = (unsigned short*)p; p += align((size_t)N * 64 * 2);
    unsigned short* h1s = (unsigned short*)p; p += align((size_t)N * 64 * 2);
    unsigned short* s2  = s1;   // alias: s1 dead after gemm1

    hipMemsetAsync(curD, 0, zbytes, stream);

    pA_scatter<<<HB + NBB, 256, 0, stream>>>(src, dst, curD, curS, pack, sloc,
                                             gids, goffs, E, NB, N, G);
    p5_build<<<2 * NB, 256, 0, stream>>>(pack, sloc, curD, curS, cols,
                                         row_offs, deg, nsrc, ndst, h, xs, N, NB);

    agg_kernel<<<4096, 256, 0, stream>>>(xs, s1, cols, row_offs, deg, N);
    gemm_kernel<0><<<(N + 63) / 64, 256, 0, stream>>>(s1, W1, b1, ndst, nsrc,
                                                      h1s, nullptr, nullptr, N);
    agg_kernel<<<4096, 256, 0, stream>>>(h1s, s2, cols, row_offs, deg, N);
    gemm_kernel<1><<<(N + 63) / 64, 256, 0, stream>>>(s2, W2, b2, ndst, nullptr,
                                                      nullptr, gids, gacc, N);
    cls_kernel<<<G, 64, 0, stream>>>(gacc, goffs, Wc, bc, out, G);
}

// Round 7
// 215.185 us; speedup vs baseline: 1.3739x; 1.3514x over previous
//
#include <hip/hip_runtime.h>
#include <hip/hip_bf16.h>

// ---------------------------------------------------------------------------
// 2-layer GraphConv (DGL norm='both') + mean_nodes pool + linear classifier.
// N=80000, E=1.28M, D=H=64, C=5, G=512.
// R18: R17's per-element pooled gemm was the bottleneck: 5.12M device-scope
// f32 atomicAdds onto a 128KB gacc = 83us at 3% VALU (cross-XCD atomics
// serialize below the non-coherent L2s, ~16ns each). gids is SORTED, so a
// gemm wave's 16 consecutive rows almost always share one graph: pool
// in-register first -- per column, sum 4 per-lane rows + shfl_xor(16,32)
// across quads -> one atomic per (wave,col) when the wave's rows are
// single-graph (90% of waves), per-element fallback otherwise. Device
// atomics 5.12M -> ~0.8M. Everything else R17/R11-verbatim.
// ---------------------------------------------------------------------------

#define NBK 160            // max buckets: ceil(80000/512)=157 <= 160
#define HB  256            // edge-pass blocks in pA
#define CAP 9216           // per-bucket slot capacity (mean 8192, +11 sigma)

typedef __attribute__((ext_vector_type(8))) short bf16x8;
typedef __attribute__((ext_vector_type(4))) float f32x4;

__device__ __forceinline__ float bflo(unsigned u) { return __uint_as_float(u << 16); }
__device__ __forceinline__ float bfhi(unsigned u) { return __uint_as_float(u & 0xffff0000u); }
__device__ __forceinline__ float bf1(unsigned short u) { return __uint_as_float((unsigned)u << 16); }
__device__ __forceinline__ unsigned short f2bf(float f) {   // RNE
    unsigned u = __float_as_uint(f);
    return (unsigned short)((u + 0x7fff + ((u >> 16) & 1)) >> 16);
}
__device__ __forceinline__ unsigned packbf(float lo, float hi) {
    return (unsigned)f2bf(lo) | ((unsigned)f2bf(hi) << 16);
}

// --- pA: single-pass bucket scatter (blocks < HB) + graph bounds (rest) ----
__global__ __launch_bounds__(256) void pA_scatter(
    const int* __restrict__ src, const int* __restrict__ dst,
    int* __restrict__ curD, int* __restrict__ curS,       // NBK cursors each, pre-zeroed
    int* __restrict__ pack, unsigned short* __restrict__ sloc,
    const int* __restrict__ gids, int* __restrict__ goffs,
    int E, int NB, int N, int G)
{
    if (blockIdx.x >= HB) {                  // fused bounds_kernel
        int i = (blockIdx.x - HB) * 256 + threadIdx.x;
        if (i >= N) return;
        int b = gids[i];
        if (i == 0) {
            for (int g = 0; g <= b; g++) goffs[g] = 0;
        } else {
            int a = gids[i - 1];
            for (int g = a + 1; g <= b; g++) goffs[g] = i;
        }
        if (i == N - 1) {
            for (int g = b + 1; g <= G; g++) goffs[g] = N;
        }
        return;
    }
    __shared__ int hd[NBK], hs[NBK];
    int t = threadIdx.x;
    for (int i = t; i < NB; i += 256) { hd[i] = 0; hs[i] = 0; }
    __syncthreads();
    int chunk = (E + HB - 1) / HB;
    int s0 = blockIdx.x * chunk, s1 = min(E, s0 + chunk);
    // vectorized histogram pass
    int q0 = s0 >> 2, q1 = s1 >> 2;          // s0 is 4-aligned (chunk%4==0)
    const int4* s4 = (const int4*)src;
    const int4* d4 = (const int4*)dst;
    for (int q = q0 + t; q < q1; q += 256) {
        int4 d = d4[q];
        int4 s = s4[q];
        atomicAdd(&hd[d.x >> 9], 1); atomicAdd(&hd[d.y >> 9], 1);
        atomicAdd(&hd[d.z >> 9], 1); atomicAdd(&hd[d.w >> 9], 1);
        atomicAdd(&hs[s.x >> 9], 1); atomicAdd(&hs[s.y >> 9], 1);
        atomicAdd(&hs[s.z >> 9], 1); atomicAdd(&hs[s.w >> 9], 1);
    }
    for (int i = (q1 << 2) + t; i < s1; i += 256) {   // tail
        atomicAdd(&hd[dst[i] >> 9], 1);
        atomicAdd(&hs[src[i] >> 9], 1);
    }
    __syncthreads();
    for (int b = t; b < NB; b += 256) {      // reserve global slots
        int cd = hd[b], cs = hs[b];
        hd[b] = cd ? atomicAdd(&curD[b], cd) : 0;   // device atomic, 1/bucket
        hs[b] = cs ? atomicAdd(&curS[b], cs) : 0;
    }
    __syncthreads();
    // vectorized scatter pass (chunk re-read is L2-hot)
    for (int q = q0 + t; q < q1; q += 256) {
        int4 d = d4[q];
        int4 s = s4[q];
        #pragma unroll
        for (int j = 0; j < 4; j++) {
            int ss = j == 0 ? s.x : j == 1 ? s.y : j == 2 ? s.z : s.w;
            int dd = j == 0 ? d.x : j == 1 ? d.y : j == 2 ? d.z : d.w;
            int bd = dd >> 9, bs = ss >> 9;
            int pd = atomicAdd(&hd[bd], 1);  // LDS atomic
            int ps = atomicAdd(&hs[bs], 1);  // LDS atomic
            if (pd < CAP) pack[(size_t)bd * CAP + pd] = ((dd & 511) << 17) | ss;
            if (ps < CAP) sloc[(size_t)bs * CAP + ps] = (unsigned short)(ss & 511);
        }
    }
    for (int i = (q1 << 2) + t; i < s1; i += 256) {   // tail
        int s = src[i], d = dst[i];
        int bd = d >> 9, bs = s >> 9;
        int pd = atomicAdd(&hd[bd], 1);
        int ps = atomicAdd(&hs[bs], 1);
        if (pd < CAP) pack[(size_t)bd * CAP + pd] = ((d & 511) << 17) | s;
        if (ps < CAP) sloc[(size_t)bs * CAP + ps] = (unsigned short)(s & 511);
    }
}

// --- p5: dst mode -> CSR (row_offs,deg,col,ndst); src mode -> nsrc+prescale -
__global__ __launch_bounds__(256) void p5_build(
    const int* __restrict__ pack, const unsigned short* __restrict__ sloc,
    const int* __restrict__ curD, const int* __restrict__ curS,
    int* __restrict__ col, int* __restrict__ row_offs, int* __restrict__ deg,
    float* __restrict__ nsrc, float* __restrict__ ndst,
    const float* __restrict__ h, unsigned short* __restrict__ xs,
    int N, int NB)
{
    __shared__ int hist[512];
    __shared__ float nsl[512];
    __shared__ int wt[4];
    int t = threadIdx.x;
    bool dmode = blockIdx.x < NB;
    int b = dmode ? blockIdx.x : blockIdx.x - NB;
    int n0 = b << 9, n1 = min(N, n0 + 512);
    hist[t] = 0; hist[t + 256] = 0;
    __syncthreads();
    int e0 = b * CAP;
    int tot = min(dmode ? curD[b] : curS[b], CAP);
    int e1 = e0 + tot;
    if (!dmode) {
        for (int i = e0 + t; i < e1; i += 256)
            atomicAdd(&hist[sloc[i]], 1);            // LDS atomic
        __syncthreads();
        for (int n = n0 + t; n < n1; n += 256) {
            float s = rsqrtf((float)max(hist[n - n0], 1));
            nsrc[n] = s;
            nsl[n - n0] = s;
        }
        __syncthreads();
        int cnt = n1 - n0;
        const float2* h2p = (const float2*)h;
        ushort2* xp = (ushort2*)xs;
        for (int i = t; i < cnt * 32; i += 256) {
            int node = i >> 5;
            float s = nsl[node];
            float2 v = h2p[(size_t)(n0 + node) * 32 + (i & 31)];
            ushort2 o;
            o.x = f2bf(v.x * s);
            o.y = f2bf(v.y * s);
            xp[(size_t)(n0 + node) * 32 + (i & 31)] = o;
        }
        return;
    }
    for (int i = e0 + t; i < e1; i += 256)
        atomicAdd(&hist[pack[i] >> 17], 1);          // LDS atomic
    __syncthreads();
    int c0 = hist[2 * t], c1 = hist[2 * t + 1];
    int v = c0 + c1;
    int lane = t & 63, w = t >> 6;
    int x = v;
    #pragma unroll
    for (int off = 1; off < 64; off <<= 1) {
        int y = __shfl_up(x, off);
        if (lane >= off) x += y;
    }
    if (lane == 63) wt[w] = x;
    __syncthreads();
    int bw = 0;
    for (int i = 0; i < w; i++) bw += wt[i];
    int excl = x - v + bw;
    int n = n0 + 2 * t;
    if (n < n1) {
        row_offs[n] = e0 + excl;
        deg[n] = c0;
        ndst[n] = rsqrtf((float)max(c0, 1));
    }
    if (n + 1 < n1) {
        row_offs[n + 1] = e0 + excl + c0;
        deg[n + 1] = c1;
        ndst[n + 1] = rsqrtf((float)max(c1, 1));
    }
    hist[2 * t] = excl;
    hist[2 * t + 1] = excl + c0;
    __syncthreads();
    for (int i = e0 + t; i < e1; i += 256) {
        int wd = pack[i];
        int pos = atomicAdd(&hist[wd >> 17], 1);     // LDS atomic
        col[e0 + pos] = wd & 0x1FFFF;
    }
}

// --- pure gather-sum with next-node prefetch (R11-verbatim) ----------------
__global__ __launch_bounds__(256) void agg_kernel(
    const unsigned short* __restrict__ z, unsigned short* __restrict__ y,
    const int* __restrict__ col, const int* __restrict__ row_offs,
    const int* __restrict__ deg, int N)
{
    int lane = threadIdx.x & 63;
    int sub  = lane >> 3;
    int li   = lane & 7;
    const uint4* x4 = (const uint4*)z;

    int wid = (blockIdx.x * 256 + threadIdx.x) >> 6;
    int nw  = (gridDim.x * 256) >> 6;

    int ro = 0, cnt = 0, idx = 0;
    if (wid < N) {
        ro = row_offs[wid];
        cnt = deg[wid];
        if (lane < min(cnt, 64)) idx = col[ro + lane];
    }
    for (int node = wid; node < N; node += nw) {
        int nnode = node + nw;
        int nro = 0, ncnt = 0;
        if (nnode < N) { nro = row_offs[nnode]; ncnt = deg[nnode]; }  // prefetch

        float a0=0.f,a1=0.f,a2=0.f,a3=0.f,a4=0.f,a5=0.f,a6=0.f,a7=0.f;
        int cc = 0;
        int cidx = idx;
        while (cc < cnt) {
            int m = min(cnt - cc, 64);
            for (int i = 0; i < m; i += 32) {
                int e1 = i + sub, e2 = i + 8 + sub, e3 = i + 16 + sub, e4 = i + 24 + sub;
                int s1 = __shfl(cidx, min(e1, m - 1));
                int s2 = __shfl(cidx, min(e2, m - 1));
                int s3 = __shfl(cidx, min(e3, m - 1));
                int s4 = __shfl(cidx, min(e4, m - 1));
                uint4 v1 = make_uint4(0u,0u,0u,0u), v2 = v1, v3 = v1, v4 = v1;
                if (e1 < m) v1 = x4[(size_t)s1 * 8 + li];
                if (e2 < m) v2 = x4[(size_t)s2 * 8 + li];
                if (e3 < m) v3 = x4[(size_t)s3 * 8 + li];
                if (e4 < m) v4 = x4[(size_t)s4 * 8 + li];
                a0 += bflo(v1.x); a1 += bfhi(v1.x);
                a2 += bflo(v1.y); a3 += bfhi(v1.y);
                a4 += bflo(v1.z); a5 += bfhi(v1.z);
                a6 += bflo(v1.w); a7 += bfhi(v1.w);
                a0 += bflo(v2.x); a1 += bfhi(v2.x);
                a2 += bflo(v2.y); a3 += bfhi(v2.y);
                a4 += bflo(v2.z); a5 += bfhi(v2.z);
                a6 += bflo(v2.w); a7 += bfhi(v2.w);
                a0 += bflo(v3.x); a1 += bfhi(v3.x);
                a2 += bflo(v3.y); a3 += bfhi(v3.y);
                a4 += bflo(v3.z); a5 += bfhi(v3.z);
                a6 += bflo(v3.w); a7 += bfhi(v3.w);
                a0 += bflo(v4.x); a1 += bfhi(v4.x);
                a2 += bflo(v4.y); a3 += bfhi(v4.y);
                a4 += bflo(v4.z); a5 += bfhi(v4.z);
                a6 += bflo(v4.w); a7 += bfhi(v4.w);
            }
            cc += 64;
            if (cc < cnt) cidx = (lane < min(cnt - cc, 64)) ? col[ro + cc + lane] : 0;
        }
        // prefetch next node's col during the reduce
        idx = 0;
        if (nnode < N && lane < min(ncnt, 64)) idx = col[nro + lane];

        #pragma unroll
        for (int off = 8; off <= 32; off <<= 1) {
            a0 += __shfl_xor(a0, off); a1 += __shfl_xor(a1, off);
            a2 += __shfl_xor(a2, off); a3 += __shfl_xor(a3, off);
            a4 += __shfl_xor(a4, off); a5 += __shfl_xor(a5, off);
            a6 += __shfl_xor(a6, off); a7 += __shfl_xor(a7, off);
        }
        if (sub == 0) {                       // 8 lanes store the 128B row
            uint4 o;
            o.x = packbf(a0, a1);
            o.y = packbf(a2, a3);
            o.z = packbf(a4, a5);
            o.w = packbf(a6, a7);
            ((uint4*)y)[(size_t)node * 8 + li] = o;
        }
        ro = nro; cnt = ncnt;
    }
}

// --- GEMM + epilogue -------------------------------------------------------
// POOL=0: Z[m] = bf16(relu(ndst[m]*(S[m]@W) + b) * nsrc[m])   (layer 1)
// POOL=1: pooled into gacc[graph][64]; wave-level pre-reduction (gids sorted:
//         a wave's 16 consecutive rows share one graph 90% of the time ->
//         one atomic per (wave,col); per-element fallback at boundaries).
template<int POOL>
__global__ __launch_bounds__(256) void gemm_kernel(
    const unsigned short* __restrict__ A, const float* __restrict__ W,
    const float* __restrict__ b, const float* __restrict__ ndst,
    const float* __restrict__ nsrc, unsigned short* __restrict__ Z,
    const int* __restrict__ gids, float* __restrict__ gacc, int M)
{
    int t = threadIdx.x, lane = t & 63, w = t >> 6;
    int col = lane & 15, quad = lane >> 4;
    bf16x8 bfrag[4][2];
    #pragma unroll
    for (int nt = 0; nt < 4; nt++)
        #pragma unroll
        for (int ks = 0; ks < 2; ks++)
            #pragma unroll
            for (int j = 0; j < 8; j++)
                bfrag[nt][ks][j] =
                    (short)f2bf(W[(ks * 32 + quad * 8 + j) * 64 + nt * 16 + col]);
    float bias[4];
    #pragma unroll
    for (int nt = 0; nt < 4; nt++) bias[nt] = b[nt * 16 + col];

    int mbase = blockIdx.x * 64 + w * 16;
    if (mbase >= M) return;                    // whole-wave exit, no barriers
    int row = min(mbase + col, M - 1);
    const uint4* a4 = (const uint4*)A;
    union { uint4 u; bf16x8 v; } a0, a1;
    a0.u = a4[(size_t)row * 8 + quad];
    a1.u = a4[(size_t)row * 8 + 4 + quad];

    float nd[4], ns[4];
    int gg[4];
    #pragma unroll
    for (int r = 0; r < 4; r++) {
        int m = min(mbase + quad * 4 + r, M - 1);
        nd[r] = ndst[m];
        ns[r] = POOL ? 1.f : nsrc[m];
        gg[r] = POOL ? gids[m] : 0;
    }
    bool uni = false;
    int g0 = 0;
    if (POOL) {
        g0 = gids[min(mbase, M - 1)];
        uni = (g0 == gids[min(mbase + 15, M - 1)]) && (mbase + 15 < M);
    }

    #pragma unroll
    for (int nt = 0; nt < 4; nt++) {
        f32x4 acc = {0.f, 0.f, 0.f, 0.f};
        acc = __builtin_amdgcn_mfma_f32_16x16x32_bf16(a0.v, bfrag[nt][0], acc, 0, 0, 0);
        acc = __builtin_amdgcn_mfma_f32_16x16x32_bf16(a1.v, bfrag[nt][1], acc, 0, 0, 0);
        if (POOL) {
            float vv[4];
            #pragma unroll
            for (int r = 0; r < 4; r++) {
                int m = mbase + quad * 4 + r;
                vv[r] = (m < M) ? fmaxf(nd[r] * acc[r] + bias[nt], 0.f) : 0.f;
            }
            if (uni) {                       // 16 rows, one graph: 1 atomic/col
                float s = (vv[0] + vv[1]) + (vv[2] + vv[3]);
                s += __shfl_xor(s, 16);
                s += __shfl_xor(s, 32);
                if (quad == 0)
                    atomicAdd(&gacc[(size_t)g0 * 64 + nt * 16 + col], s);
            } else {                         // boundary wave (rare)
                #pragma unroll
                for (int r = 0; r < 4; r++) {
                    int m = mbase + quad * 4 + r;
                    if (m < M)
                        atomicAdd(&gacc[(size_t)gg[r] * 64 + nt * 16 + col], vv[r]);
                }
            }
        } else {
            #pragma unroll
            for (int r = 0; r < 4; r++) {
                int m = mbase + quad * 4 + r;
                if (m < M) {
                    float v = fmaxf(nd[r] * acc[r] + bias[nt], 0.f);
                    Z[(size_t)m * 64 + nt * 16 + col] = f2bf(v * ns[r]);
                }
            }
        }
    }
}

// --- per-graph mean + 64x5 classifier (1 wave per graph) -------------------
__global__ __launch_bounds__(64) void cls_kernel(
    const float* __restrict__ gacc, const int* __restrict__ goffs,
    const float* __restrict__ Wc, const float* __restrict__ bc,
    float* __restrict__ out, int G)
{
    int g = blockIdx.x;
    int lane = threadIdx.x;
    float cnt = (float)max(goffs[g + 1] - goffs[g], 1);
    float mean = gacc[(size_t)g * 64 + lane] / cnt;
    #pragma unroll
    for (int c = 0; c < 5; c++) {
        float p = mean * Wc[lane * 5 + c];
        #pragma unroll
        for (int off = 32; off; off >>= 1) p += __shfl_down(p, off);
        if (lane == 0) out[g * 5 + c] = p + bc[c];
    }
}

extern "C" void kernel_launch(void* const* d_in, const int* in_sizes, int n_in,
                              void* d_out, int out_size, void* d_ws, size_t ws_size,
                              hipStream_t stream)
{
    const float* h    = (const float*)d_in[0];
    const int*   src  = (const int*)d_in[1];
    const int*   dst  = (const int*)d_in[2];
    const int*   gids = (const int*)d_in[3];
    const float* W1   = (const float*)d_in[4];
    const float* b1   = (const float*)d_in[5];
    const float* W2   = (const float*)d_in[6];
    const float* b2   = (const float*)d_in[7];
    const float* Wc   = (const float*)d_in[8];
    const float* bc   = (const float*)d_in[9];
    float* out = (float*)d_out;

    const int N = in_sizes[0] / 64;
    const int E = in_sizes[1];
    const int G = out_size / 5;
    const int NB = (N + 511) >> 9;
    const int NBB = (N + 255) / 256;        // bounds blocks

    auto align = [](size_t x) { return (x + 255) & ~(size_t)255; };
    char* p = (char*)d_ws;
    // curD | curS | gacc contiguous -> single memset clears all three
    int* curD    = (int*)p;
    int* curS    = curD + NBK;
    float* gacc  = (float*)(p + (size_t)2 * NBK * 4);   // G*64 floats
    size_t zbytes = (size_t)2 * NBK * 4 + (size_t)G * 64 * 4;
    p += align(zbytes);
    int* row_offs= (int*)p;            p += align((size_t)N * 4);
    int* deg     = (int*)p;            p += align((size_t)N * 4);
    float* nsrc  = (float*)p;          p += align((size_t)N * 4);
    float* ndst  = (float*)p;          p += align((size_t)N * 4);
    int* goffs   = (int*)p;            p += align((size_t)(G + 1) * 4);
    int* pack    = (int*)p;            p += align((size_t)NBK * CAP * 4);
    unsigned short* sloc = (unsigned short*)p; p += align((size_t)NBK * CAP * 2);
    int* cols    = (int*)p;            p += align((size_t)NBK * CAP * 4);
    unsigned short* xs  = (unsigned short*)p; p += align((size_t)N * 64 * 2);
    unsigned short* s1  = (unsigned short*)p; p += align((size_t)N * 64 * 2);
    unsigned short* h1s = (unsigned short*)p; p += align((size_t)N * 64 * 2);
    unsigned short* s2  = s1;   // alias: s1 dead after gemm1

    hipMemsetAsync(curD, 0, zbytes, stream);

    pA_scatter<<<HB + NBB, 256, 0, stream>>>(src, dst, curD, curS, pack, sloc,
                                             gids, goffs, E, NB, N, G);
    p5_build<<<2 * NB, 256, 0, stream>>>(pack, sloc, curD, curS, cols,
                                         row_offs, deg, nsrc, ndst, h, xs, N, NB);

    agg_kernel<<<4096, 256, 0, stream>>>(xs, s1, cols, row_offs, deg, N);
    gemm_kernel<0><<<(N + 63) / 64, 256, 0, stream>>>(s1, W1, b1, ndst, nsrc,
                                                      h1s, nullptr, nullptr, N);
    agg_kernel<<<4096, 256, 0, stream>>>(h1s, s2, cols, row_offs, deg, N);
    gemm_kernel<1><<<(N + 63) / 64, 256, 0, stream>>>(s2, W2, b2, ndst, nullptr,
                                                      nullptr, gids, gacc, N);
    cls_kernel<<<G, 64, 0, stream>>>(gacc, goffs, Wc, bc, out, G);
}